// Round 7
// baseline (177.183 us; speedup 1.0000x reference)
//
#include <hip/hip_runtime.h>
#include <hip/hip_fp16.h>

typedef __fp16 h2_t __attribute__((ext_vector_type(2)));
typedef _Float16 f16x8 __attribute__((ext_vector_type(8)));
typedef float f32x4 __attribute__((ext_vector_type(4)));
typedef float v4f __attribute__((ext_vector_type(4)));    // clang vec: ok for nontemporal
typedef unsigned int uint32;

#define S_DIM 8192
#define B_DIM 8192
#define Q_DIM 64
#define A_DIM 1024
#define H_DIM 64
#define N_GATES 576

#define MT 64                  // rows per block (4 waves x 16 rows)
#define KSPLIT 8
#define KC (S_DIM / KSPLIT)    // 1024 k per block
#define NSTEP (KC / 32)        // 32 steps of 32 k
#define NCHUNK 8
#define CHUNK (N_GATES / NCHUNK)   // 72

__device__ __forceinline__ uint32 pk_f16(float x, float y) {
    h2_t h = __builtin_amdgcn_cvt_pkrtz(x, y);
    return __builtin_bit_cast(uint32, h);
}

__device__ __forceinline__ f32x4 mfma16(uint4 a, uint4 b, f32x4 c) {
    return __builtin_amdgcn_mfma_f32_16x16x32_f16(
        __builtin_bit_cast(f16x8, a), __builtin_bit_cast(f16x8, b), c, 0, 0, 0);
}

// Pack enc_w [64][8192] f32 -> MFMA B-fragment order f16:
// bpack[(kt*4 + nt)*64 + lane] = B[n = nt*16 + lane%16][k = kt*32 + (lane/16)*8 .. +8]
__global__ void k_packB(const float* __restrict__ encw, uint4* __restrict__ bpack) {
    const int gid  = blockIdx.x * 256 + threadIdx.x;   // 65536 total
    const int lane = gid & 63;
    const int nt   = (gid >> 6) & 3;
    const int kt   = gid >> 8;                          // 0..255
    const int n = nt * 16 + (lane & 15);
    const int k = kt * 32 + (lane >> 4) * 8;
    const float* p = encw + (size_t)n * S_DIM + k;
    float4 x0 = *(const float4*)p;
    float4 x1 = *(const float4*)(p + 4);
    uint4 r;
    r.x = pk_f16(x0.x, x0.y);
    r.y = pk_f16(x0.z, x0.w);
    r.z = pk_f16(x1.x, x1.y);
    r.w = pk_f16(x1.z, x1.w);
    bpack[gid] = r;
}

// K1: partial[ks][m][n] = state[m, ks-range] . enc_w[n, ks-range]
// Barrier-free, LDS-free; 4-step-deep A software pipeline, B double-buffered.
__global__ __launch_bounds__(256, 4) void k_gemm(
        const float* __restrict__ state, const uint4* __restrict__ bpack,
        float* __restrict__ partial) {
    const int t  = threadIdx.x;
    const int w  = t >> 6;
    const int l  = t & 63;
    const int m0 = blockIdx.x * MT;
    const int ks = blockIdx.y;
    const int k0 = ks * KC;

    // A fragment coords (HW-validated): row = lane&15, k-group = (lane>>4)*8
    const int row = m0 + w * 16 + (l & 15);
    const float* pa = state + (size_t)row * S_DIM + k0 + (l >> 4) * 8;
    const uint4* pb = bpack + (size_t)(k0 >> 5) * 256 + l;

    f32x4 acc0 = {}, acc1 = {}, acc2 = {}, acc3 = {};

    v4f fa0a, fa0b, fa1a, fa1b, fa2a, fa2b, fa3a, fa3b;     // 4-step A pipeline
    uint4 fb0a, fb0b, fb0c, fb0d, fb1a, fb1b, fb1c, fb1d;   // 2-step B pipeline

#define LA(P, S) do { \
        fa##P##a = __builtin_nontemporal_load((const v4f*)(pa + (S) * 32)); \
        fa##P##b = __builtin_nontemporal_load((const v4f*)(pa + (S) * 32 + 4)); } while (0)
#define LB(P, S) do { \
        fb##P##a = pb[(size_t)((S) * 4 + 0) * 64]; \
        fb##P##b = pb[(size_t)((S) * 4 + 1) * 64]; \
        fb##P##c = pb[(size_t)((S) * 4 + 2) * 64]; \
        fb##P##d = pb[(size_t)((S) * 4 + 3) * 64]; } while (0)
#define STEP(P, Q) do { \
        uint4 af; \
        af.x = pk_f16(fa##P##a.x, fa##P##a.y); \
        af.y = pk_f16(fa##P##a.z, fa##P##a.w); \
        af.z = pk_f16(fa##P##b.x, fa##P##b.y); \
        af.w = pk_f16(fa##P##b.z, fa##P##b.w); \
        acc0 = mfma16(af, fb##Q##a, acc0); \
        acc1 = mfma16(af, fb##Q##b, acc1); \
        acc2 = mfma16(af, fb##Q##c, acc2); \
        acc3 = mfma16(af, fb##Q##d, acc3); } while (0)

    LA(0, 0); LA(1, 1); LA(2, 2); LA(3, 3);
    LB(0, 0);

    for (int s = 0; s < NSTEP; s += 4) {
        LB(1, s + 1);
        STEP(0, 0);
        if (s + 4 < NSTEP) LA(0, s + 4);
        LB(0, s + 2);
        STEP(1, 1);
        if (s + 5 < NSTEP) LA(1, s + 5);
        LB(1, s + 3);
        STEP(2, 0);
        if (s + 6 < NSTEP) LA(2, s + 6);
        if (s + 4 < NSTEP) LB(0, s + 4);
        STEP(3, 1);
        if (s + 7 < NSTEP) LA(3, s + 7);
    }
#undef LA
#undef LB
#undef STEP

    // C/D: col = lane&15, row = (lane>>4)*4 + reg  (verified mapping)
    float* pc = partial + (size_t)ks * (B_DIM * Q_DIM);
    const int mr = m0 + w * 16 + (l >> 4) * 4;
    const int nc = l & 15;
    f32x4 accs[4] = {acc0, acc1, acc2, acc3};
#pragma unroll
    for (int nt = 0; nt < 4; ++nt)
#pragma unroll
        for (int r = 0; r < 4; ++r)
            pc[(size_t)(mr + r) * Q_DIM + nt * 16 + nc] = accs[nt][r];
}

// K2: x[r][q] = sum_ks partial + bias; softmax over q; per-block column sums
__global__ void k_softmax(const float* __restrict__ partial,
                          const float* __restrict__ encb,
                          float* __restrict__ colsum_parts) {
    __shared__ float red[4][64];
    const int lane = threadIdx.x & 63;
    const int wv   = threadIdx.x >> 6;
    const float eb = encb[lane];
    float accq = 0.f;
    for (int i = 0; i < 8; ++i) {
        const int r = blockIdx.x * 32 + i * 4 + wv;
        float x = eb;
#pragma unroll
        for (int ks = 0; ks < KSPLIT; ++ks)
            x += partial[(size_t)ks * (B_DIM * Q_DIM) + (size_t)r * Q_DIM + lane];
        float m = x;
        for (int o = 32; o > 0; o >>= 1) m = fmaxf(m, __shfl_xor(m, o));
        float e = __expf(x - m);
        float s = e;
        for (int o = 32; o > 0; o >>= 1) s += __shfl_xor(s, o);
        accq += e / s;
    }
    red[wv][lane] = accq;
    __syncthreads();
    if (threadIdx.x < 64) {
        colsum_parts[blockIdx.x * 64 + lane] =
            red[0][lane] + red[1][lane] + red[2][lane] + red[3][lane];
    }
}

// K3: fused tail — colsum reduce, gates (chunked polynomial + conv tree),
// measurements, hidden, output. One block, 1024 threads.
__global__ void k_tail(const float* __restrict__ colsum_parts,
                       const float* __restrict__ qp,
                       const float* __restrict__ mo,
                       const float* __restrict__ w1, const float* __restrict__ b1,
                       const float* __restrict__ w2, const float* __restrict__ b2,
                       float* __restrict__ out) {
    __shared__ float t0[64];
    __shared__ float tv[64];
    __shared__ float pA[8][64];
    __shared__ float pB[4][64];
    __shared__ float cs[N_GATES], ss[N_GATES];
    __shared__ float meas[A_DIM];        // also used as colsum scratch first
    __shared__ float hvec[64];
    const int t    = threadIdx.x;
    const int lane = t & 63;
    const int wv   = t >> 6;             // 0..15

    if (t < N_GATES) {
        float th = qp[t] * 0.5f;
        cs[t] = __cosf(th);
        ss[t] = __sinf(th);
    }
    {
        float c = 0.f;
#pragma unroll
        for (int i = 0; i < 16; ++i)
            c += colsum_parts[(wv + i * 16) * 64 + lane];
        meas[wv * 64 + lane] = c;
    }
    __syncthreads();
    if (t < 64) {
        float s = 0.f;
#pragma unroll
        for (int g = 0; g < 16; ++g) s += meas[g * 64 + t];
        t0[t] = s;
    }
    __syncthreads();

    // chunk polynomials: wave c computes P_c = prod_{g in chunk} (c_g + s_g x) mod x^64-1
    if (wv < NCHUNK) {
        float p = (lane == 0) ? 1.f : 0.f;
        const int g0 = wv * CHUNK;
        for (int g = 0; g < CHUNK; ++g) {
            float prev = __shfl(p, (lane + 63) & 63);
            p = fmaf(cs[g0 + g], p, ss[g0 + g] * prev);
        }
        pA[wv][lane] = p;
    }
    __syncthreads();
    if (wv < 4) {
        float r = 0.f;
        for (int i = 0; i < 64; ++i)
            r += pA[2 * wv][i] * pA[2 * wv + 1][(lane - i) & 63];
        pB[wv][lane] = r;
    }
    __syncthreads();
    if (wv < 2) {
        float r = 0.f;
        for (int i = 0; i < 64; ++i)
            r += pB[2 * wv][i] * pB[2 * wv + 1][(lane - i) & 63];
        pA[wv][lane] = r;
    }
    __syncthreads();
    if (wv == 0) {
        float r = 0.f;
        for (int i = 0; i < 64; ++i)
            r += pA[0][i] * pA[1][(lane - i) & 63];
        pB[0][lane] = r;
    }
    __syncthreads();
    if (wv == 0) {
        float r = 0.f;
        for (int i = 0; i < 64; ++i)
            r += pB[0][i] * t0[(lane - i) & 63];
        tv[lane] = r;
    }
    __syncthreads();

    // measurements: meas[a] = sum_q tv[q] * mo[a][q][0]
    {
        const float4* mo4 = (const float4*)(mo + (size_t)t * 128);
        float v = 0.f;
#pragma unroll
        for (int i = 0; i < 32; ++i) {
            float4 m4 = mo4[i];
            v = fmaf(tv[2 * i], m4.x, v);
            v = fmaf(tv[2 * i + 1], m4.z, v);
        }
        meas[t] = v;
    }
    __syncthreads();

    // hidden: 16 threads per j
    {
        const int j    = t >> 4;
        const int part = t & 15;
        const float4* w14 = (const float4*)(w1 + (size_t)j * A_DIM + part * 64);
        const float4* m4  = (const float4*)(meas + part * 64);
        float v = 0.f;
#pragma unroll
        for (int i = 0; i < 16; ++i) {
            float4 a = w14[i];
            float4 b = m4[i];
            v += a.x * b.x + a.y * b.y + a.z * b.z + a.w * b.w;
        }
        for (int o = 8; o > 0; o >>= 1) v += __shfl_xor(v, o);
        if (part == 0) hvec[j] = fmaxf(v + b1[j], 0.f);
    }
    __syncthreads();

    // output: out[a] = sum_j hvec[j] * w2[a][j] + b2[a]
    {
        const float4* w24 = (const float4*)(w2 + (size_t)t * H_DIM);
        float v = 0.f;
#pragma unroll
        for (int i = 0; i < 16; ++i) {
            float4 a = w24[i];
            v += a.x * hvec[4 * i] + a.y * hvec[4 * i + 1] +
                 a.z * hvec[4 * i + 2] + a.w * hvec[4 * i + 3];
        }
        out[t] = v + b2[t];
    }
}

extern "C" void kernel_launch(void* const* d_in, const int* in_sizes, int n_in,
                              void* d_out, int out_size, void* d_ws, size_t ws_size,
                              hipStream_t stream) {
    const float* state = (const float*)d_in[0];
    const float* encw  = (const float*)d_in[1];
    const float* encb  = (const float*)d_in[2];
    const float* qp    = (const float*)d_in[3];
    const float* mo    = (const float*)d_in[4];
    const float* w1    = (const float*)d_in[5];
    const float* b1    = (const float*)d_in[6];
    const float* w2    = (const float*)d_in[7];
    const float* b2    = (const float*)d_in[8];
    float* out = (float*)d_out;

    float* ws           = (float*)d_ws;
    float* colsum_parts = ws;                        // 256*64 = 16384 floats
    float* partial      = ws + 16384;                // 8 * 8192*64 floats (16 MB)
    uint4* bpack        = (uint4*)(partial + (size_t)KSPLIT * B_DIM * Q_DIM);  // 1 MB

    k_packB<<<dim3(256), dim3(256), 0, stream>>>(encw, bpack);
    k_gemm<<<dim3(B_DIM / MT, KSPLIT), dim3(256), 0, stream>>>(state, bpack, partial);
    k_softmax<<<dim3(256), dim3(256), 0, stream>>>(partial, encb, colsum_parts);
    k_tail<<<dim3(1), dim3(1024), 0, stream>>>(colsum_parts, qp, mo, w1, b1, w2, b2, out);
}

// Round 8
// 136.697 us; speedup vs baseline: 1.2962x; 1.2962x over previous
//
#include <hip/hip_runtime.h>
#include <hip/hip_fp16.h>

typedef __fp16 h2_t __attribute__((ext_vector_type(2)));
typedef _Float16 f16x8 __attribute__((ext_vector_type(8)));
typedef float f32x4 __attribute__((ext_vector_type(4)));
typedef float v4f __attribute__((ext_vector_type(4)));
typedef unsigned int uint32;

#define S_DIM 8192
#define B_DIM 8192
#define Q_DIM 64
#define A_DIM 1024
#define H_DIM 64
#define N_GATES 576

#define MT 64                  // rows per block (4 waves x 16 rows)
#define KSPLIT 8
#define KC (S_DIM / KSPLIT)    // 1024 k per block
#define BK 64                  // k per LDS step
#define NSTEP (KC / BK)        // 16 (even)
#define NCHUNK 8
#define CHUNK (N_GATES / NCHUNK)   // 72

__device__ __forceinline__ uint32 pk_f16(float x, float y) {
    h2_t h = __builtin_amdgcn_cvt_pkrtz(x, y);
    return __builtin_bit_cast(uint32, h);
}

__device__ __forceinline__ f32x4 mfma16(uint4 a, uint4 b, f32x4 c) {
    return __builtin_amdgcn_mfma_f32_16x16x32_f16(
        __builtin_bit_cast(f16x8, a), __builtin_bit_cast(f16x8, b), c, 0, 0, 0);
}

// Pack enc_w [64][8192] f32 -> MFMA B-fragment order f16:
// bpack[(kt*4 + nt)*64 + lane] = B[n = nt*16 + lane%16][k = kt*32 + (lane/16)*8 .. +8]
__global__ void k_packB(const float* __restrict__ encw, uint4* __restrict__ bpack) {
    const int gid  = blockIdx.x * 256 + threadIdx.x;   // 65536 total
    const int lane = gid & 63;
    const int nt   = (gid >> 6) & 3;
    const int kt   = gid >> 8;                          // 0..255
    const int n = nt * 16 + (lane & 15);
    const int k = kt * 32 + (lane >> 4) * 8;
    const float* p = encw + (size_t)n * S_DIM + k;
    float4 x0 = *(const float4*)p;
    float4 x1 = *(const float4*)(p + 4);
    uint4 r;
    r.x = pk_f16(x0.x, x0.y);
    r.y = pk_f16(x0.z, x0.w);
    r.z = pk_f16(x1.x, x1.y);
    r.w = pk_f16(x1.z, x1.w);
    bpack[gid] = r;
}

// K1: partial[ks][m][n] = state[m, ks-range] . enc_w[n, ks-range]
// r3 trunk: LDS double-buffered A; NEW: raw s_barrier (no vmcnt drain),
// one barrier per step, 2-step-ahead A prefetch in named reg sets.
__global__ __launch_bounds__(256, 4) void k_gemm(
        const float* __restrict__ state, const uint4* __restrict__ bpack,
        float* __restrict__ partial) {
    // 64 rows x 64 halfs (32 u32) padded to 36 u32: 2-way-only bank aliasing (free)
    __shared__ __align__(16) uint32 As[2][MT][36];
    const int t  = threadIdx.x;
    const int w  = t >> 6;
    const int l  = t & 63;
    const int m0 = blockIdx.x * MT;
    const int ks = blockIdx.y;
    const int k0 = ks * KC;

    // A staging: thread t loads row t/4, 16 consecutive floats at col (t%4)*16
    const int ar = t >> 2;
    const int ac = (t & 3) * 16;
    const float* pa = state + (size_t)(m0 + ar) * S_DIM + k0 + ac;

    // B fragments, pre-packed, L2-resident
    const uint4* pb = bpack + (size_t)(k0 >> 5) * 256 + l;

    // compute-side fragment coords (HW-validated mapping)
    const int frow = w * 16 + (l & 15);
    const int fc   = (l >> 4) * 4;

    f32x4 acc0 = {}, acc1 = {}, acc2 = {}, acc3 = {};
    v4f a0, a1, a2, a3, b0, b1, b2, b3;      // two named A prefetch sets

#define LOADA(P0, P1, P2, P3, S) do { \
        const float* p_ = pa + (S) * BK; \
        P0 = *(const v4f*)(p_);      P1 = *(const v4f*)(p_ + 4); \
        P2 = *(const v4f*)(p_ + 8);  P3 = *(const v4f*)(p_ + 12); } while (0)

#define CVTW(P0, P1, P2, P3, BUF) do { \
        uint4 w0_, w1_; \
        w0_.x = pk_f16(P0.x, P0.y); w0_.y = pk_f16(P0.z, P0.w); \
        w0_.z = pk_f16(P1.x, P1.y); w0_.w = pk_f16(P1.z, P1.w); \
        w1_.x = pk_f16(P2.x, P2.y); w1_.y = pk_f16(P2.z, P2.w); \
        w1_.z = pk_f16(P3.x, P3.y); w1_.w = pk_f16(P3.z, P3.w); \
        *(uint4*)&As[BUF][ar][ac >> 1]       = w0_; \
        *(uint4*)&As[BUF][ar][(ac >> 1) + 4] = w1_; } while (0)

// LDS writes must be visible; in-flight GLOBAL loads may cross (no vmcnt drain)
#define BARRIER() do { \
        asm volatile("s_waitcnt lgkmcnt(0)" ::: "memory"); \
        __builtin_amdgcn_s_barrier(); } while (0)

#define COMPUTE(BUF, S) do { \
        uint4 bf0 = pb[(size_t)(((S) * 2 + 0) * 4 + 0) * 64]; \
        uint4 bf1 = pb[(size_t)(((S) * 2 + 0) * 4 + 1) * 64]; \
        uint4 bf2 = pb[(size_t)(((S) * 2 + 0) * 4 + 2) * 64]; \
        uint4 bf3 = pb[(size_t)(((S) * 2 + 0) * 4 + 3) * 64]; \
        uint4 bf4 = pb[(size_t)(((S) * 2 + 1) * 4 + 0) * 64]; \
        uint4 bf5 = pb[(size_t)(((S) * 2 + 1) * 4 + 1) * 64]; \
        uint4 bf6 = pb[(size_t)(((S) * 2 + 1) * 4 + 2) * 64]; \
        uint4 bf7 = pb[(size_t)(((S) * 2 + 1) * 4 + 3) * 64]; \
        uint4 af0 = *(const uint4*)&As[BUF][frow][fc]; \
        uint4 af1 = *(const uint4*)&As[BUF][frow][fc + 16]; \
        acc0 = mfma16(af0, bf0, acc0); acc1 = mfma16(af0, bf1, acc1); \
        acc2 = mfma16(af0, bf2, acc2); acc3 = mfma16(af0, bf3, acc3); \
        acc0 = mfma16(af1, bf4, acc0); acc1 = mfma16(af1, bf5, acc1); \
        acc2 = mfma16(af1, bf6, acc2); acc3 = mfma16(af1, bf7, acc3); } while (0)

    // prologue: steps 0 and 1 in flight; step 0 staged
    LOADA(a0, a1, a2, a3, 0);
    LOADA(b0, b1, b2, b3, 1);
    CVTW(a0, a1, a2, a3, 0);
    BARRIER();

    for (int s = 0; s < NSTEP; s += 2) {
        if (s + 2 < NSTEP) LOADA(a0, a1, a2, a3, s + 2);   // prefetch depth 2
        COMPUTE(0, s);
        CVTW(b0, b1, b2, b3, 1);                           // stage s+1
        BARRIER();
        if (s + 3 < NSTEP) LOADA(b0, b1, b2, b3, s + 3);
        COMPUTE(1, s + 1);
        if (s + 2 < NSTEP) CVTW(a0, a1, a2, a3, 0);        // stage s+2
        BARRIER();
    }
#undef LOADA
#undef CVTW
#undef BARRIER
#undef COMPUTE

    // C/D: col = lane&15, row = (lane>>4)*4 + reg  (verified mapping)
    float* pc = partial + (size_t)ks * (B_DIM * Q_DIM);
    const int mr = m0 + w * 16 + (l >> 4) * 4;
    const int nc = l & 15;
    f32x4 accs[4] = {acc0, acc1, acc2, acc3};
#pragma unroll
    for (int nt = 0; nt < 4; ++nt)
#pragma unroll
        for (int r = 0; r < 4; ++r)
            pc[(size_t)(mr + r) * Q_DIM + nt * 16 + nc] = accs[nt][r];
}

// K2: x[r][q] = sum_ks partial + bias; softmax over q; per-block column sums
__global__ void k_softmax(const float* __restrict__ partial,
                          const float* __restrict__ encb,
                          float* __restrict__ colsum_parts) {
    __shared__ float red[4][64];
    const int lane = threadIdx.x & 63;
    const int wv   = threadIdx.x >> 6;
    const float eb = encb[lane];
    float accq = 0.f;
    for (int i = 0; i < 8; ++i) {
        const int r = blockIdx.x * 32 + i * 4 + wv;
        float x = eb;
#pragma unroll
        for (int ks = 0; ks < KSPLIT; ++ks)
            x += partial[(size_t)ks * (B_DIM * Q_DIM) + (size_t)r * Q_DIM + lane];
        float m = x;
        for (int o = 32; o > 0; o >>= 1) m = fmaxf(m, __shfl_xor(m, o));
        float e = __expf(x - m);
        float s = e;
        for (int o = 32; o > 0; o >>= 1) s += __shfl_xor(s, o);
        accq += e / s;
    }
    red[wv][lane] = accq;
    __syncthreads();
    if (threadIdx.x < 64) {
        colsum_parts[blockIdx.x * 64 + lane] =
            red[0][lane] + red[1][lane] + red[2][lane] + red[3][lane];
    }
}

// K3: fused tail — colsum reduce, gates (chunked polynomial + conv tree),
// measurements, hidden, output. One block, 1024 threads.
__global__ void k_tail(const float* __restrict__ colsum_parts,
                       const float* __restrict__ qp,
                       const float* __restrict__ mo,
                       const float* __restrict__ w1, const float* __restrict__ b1,
                       const float* __restrict__ w2, const float* __restrict__ b2,
                       float* __restrict__ out) {
    __shared__ float t0[64];
    __shared__ float tv[64];
    __shared__ float pA[8][64];
    __shared__ float pB[4][64];
    __shared__ float cs[N_GATES], ss[N_GATES];
    __shared__ float meas[A_DIM];        // also used as colsum scratch first
    __shared__ float hvec[64];
    const int t    = threadIdx.x;
    const int lane = t & 63;
    const int wv   = t >> 6;             // 0..15

    if (t < N_GATES) {
        float th = qp[t] * 0.5f;
        cs[t] = __cosf(th);
        ss[t] = __sinf(th);
    }
    {
        float c = 0.f;
#pragma unroll
        for (int i = 0; i < 16; ++i)
            c += colsum_parts[(wv + i * 16) * 64 + lane];
        meas[wv * 64 + lane] = c;
    }
    __syncthreads();
    if (t < 64) {
        float s = 0.f;
#pragma unroll
        for (int g = 0; g < 16; ++g) s += meas[g * 64 + t];
        t0[t] = s;
    }
    __syncthreads();

    // chunk polynomials: wave c computes P_c = prod_{g in chunk} (c_g + s_g x) mod x^64-1
    if (wv < NCHUNK) {
        float p = (lane == 0) ? 1.f : 0.f;
        const int g0 = wv * CHUNK;
        for (int g = 0; g < CHUNK; ++g) {
            float prev = __shfl(p, (lane + 63) & 63);
            p = fmaf(cs[g0 + g], p, ss[g0 + g] * prev);
        }
        pA[wv][lane] = p;
    }
    __syncthreads();
    if (wv < 4) {
        float r = 0.f;
        for (int i = 0; i < 64; ++i)
            r += pA[2 * wv][i] * pA[2 * wv + 1][(lane - i) & 63];
        pB[wv][lane] = r;
    }
    __syncthreads();
    if (wv < 2) {
        float r = 0.f;
        for (int i = 0; i < 64; ++i)
            r += pB[2 * wv][i] * pB[2 * wv + 1][(lane - i) & 63];
        pA[wv][lane] = r;
    }
    __syncthreads();
    if (wv == 0) {
        float r = 0.f;
        for (int i = 0; i < 64; ++i)
            r += pA[0][i] * pA[1][(lane - i) & 63];
        pB[0][lane] = r;
    }
    __syncthreads();
    if (wv == 0) {
        float r = 0.f;
        for (int i = 0; i < 64; ++i)
            r += pB[0][i] * t0[(lane - i) & 63];
        tv[lane] = r;
    }
    __syncthreads();

    // measurements: meas[a] = sum_q tv[q] * mo[a][q][0]
    {
        const float4* mo4 = (const float4*)(mo + (size_t)t * 128);
        float v = 0.f;
#pragma unroll
        for (int i = 0; i < 32; ++i) {
            float4 m4 = mo4[i];
            v = fmaf(tv[2 * i], m4.x, v);
            v = fmaf(tv[2 * i + 1], m4.z, v);
        }
        meas[t] = v;
    }
    __syncthreads();

    // hidden: 16 threads per j
    {
        const int j    = t >> 4;
        const int part = t & 15;
        const float4* w14 = (const float4*)(w1 + (size_t)j * A_DIM + part * 64);
        const float4* m4  = (const float4*)(meas + part * 64);
        float v = 0.f;
#pragma unroll
        for (int i = 0; i < 16; ++i) {
            float4 a = w14[i];
            float4 b = m4[i];
            v += a.x * b.x + a.y * b.y + a.z * b.z + a.w * b.w;
        }
        for (int o = 8; o > 0; o >>= 1) v += __shfl_xor(v, o);
        if (part == 0) hvec[j] = fmaxf(v + b1[j], 0.f);
    }
    __syncthreads();

    // output: out[a] = sum_j hvec[j] * w2[a][j] + b2[a]
    {
        const float4* w24 = (const float4*)(w2 + (size_t)t * H_DIM);
        float v = 0.f;
#pragma unroll
        for (int i = 0; i < 16; ++i) {
            float4 a = w24[i];
            v += a.x * hvec[4 * i] + a.y * hvec[4 * i + 1] +
                 a.z * hvec[4 * i + 2] + a.w * hvec[4 * i + 3];
        }
        out[t] = v + b2[t];
    }
}

extern "C" void kernel_launch(void* const* d_in, const int* in_sizes, int n_in,
                              void* d_out, int out_size, void* d_ws, size_t ws_size,
                              hipStream_t stream) {
    const float* state = (const float*)d_in[0];
    const float* encw  = (const float*)d_in[1];
    const float* encb  = (const float*)d_in[2];
    const float* qp    = (const float*)d_in[3];
    const float* mo    = (const float*)d_in[4];
    const float* w1    = (const float*)d_in[5];
    const float* b1    = (const float*)d_in[6];
    const float* w2    = (const float*)d_in[7];
    const float* b2    = (const float*)d_in[8];
    float* out = (float*)d_out;

    float* ws           = (float*)d_ws;
    float* colsum_parts = ws;                        // 256*64 = 16384 floats
    float* partial      = ws + 16384;                // 8 * 8192*64 floats (16 MB)
    uint4* bpack        = (uint4*)(partial + (size_t)KSPLIT * B_DIM * Q_DIM);  // 1 MB

    k_packB<<<dim3(256), dim3(256), 0, stream>>>(encw, bpack);
    k_gemm<<<dim3(B_DIM / MT, KSPLIT), dim3(256), 0, stream>>>(state, bpack, partial);
    k_softmax<<<dim3(256), dim3(256), 0, stream>>>(partial, encb, colsum_parts);
    k_tail<<<dim3(1), dim3(1024), 0, stream>>>(colsum_parts, qp, mo, w1, b1, w2, b2, out);
}

// Round 9
// 102.115 us; speedup vs baseline: 1.7351x; 1.3387x over previous
//
#include <hip/hip_runtime.h>
#include <hip/hip_fp16.h>

typedef __fp16 h2_t __attribute__((ext_vector_type(2)));
typedef _Float16 f16x8 __attribute__((ext_vector_type(8)));
typedef float f32x4 __attribute__((ext_vector_type(4)));
typedef unsigned int uint32;

#define S_DIM 8192
#define B_DIM 8192
#define Q_DIM 64
#define A_DIM 1024
#define H_DIM 64
#define N_GATES 576

#define MT 64                  // rows per block
#define KSPLIT 8
#define KC (S_DIM / KSPLIT)    // 1024 k per block
#define BK 64                  // k per staged step
#define NSTEP (KC / BK)        // 16
#define NCHUNK 4
#define CHUNK (N_GATES / NCHUNK)   // 144

__device__ __forceinline__ uint32 pk_f16(float x, float y) {
    h2_t h = __builtin_amdgcn_cvt_pkrtz(x, y);
    return __builtin_bit_cast(uint32, h);
}

__device__ __forceinline__ f32x4 mfma16(uint4 a, uint4 b, f32x4 c) {
    return __builtin_amdgcn_mfma_f32_16x16x32_f16(
        __builtin_bit_cast(f16x8, a), __builtin_bit_cast(f16x8, b), c, 0, 0, 0);
}

// Pack enc_w [64][8192] f32 -> MFMA B-fragment order f16 (r3-verified)
__global__ void k_packB(const float* __restrict__ encw, uint4* __restrict__ bpack) {
    const int gid  = blockIdx.x * 256 + threadIdx.x;   // 65536 total
    const int lane = gid & 63;
    const int nt   = (gid >> 6) & 3;
    const int kt   = gid >> 8;                          // 0..255
    const int n = nt * 16 + (lane & 15);
    const int k = kt * 32 + (lane >> 4) * 8;
    const float* p = encw + (size_t)n * S_DIM + k;
    float4 x0 = *(const float4*)p;
    float4 x1 = *(const float4*)(p + 4);
    uint4 r;
    r.x = pk_f16(x0.x, x0.y);
    r.y = pk_f16(x0.z, x0.w);
    r.z = pk_f16(x1.x, x1.y);
    r.w = pk_f16(x1.z, x1.w);
    bpack[gid] = r;
}

// k_M2: per-block recompute gate filter f[64] (input-only), then
// M2[a][j] = sum_i f[i] * mo[a][(j+i)&63][0]   (4 a-rows per block)
__global__ void k_M2(const float* __restrict__ qp, const float* __restrict__ mo,
                     float* __restrict__ M2) {
    __shared__ float cs[N_GATES], ss[N_GATES];
    __shared__ float pA[NCHUNK][64];
    __shared__ float pB[2][64];
    __shared__ float f[64];
    __shared__ float rows[4][64];
    const int t    = threadIdx.x;          // 256
    const int lane = t & 63;
    const int wv   = t >> 6;               // 0..3

    for (int g = t; g < N_GATES; g += 256) {
        float th = qp[g] * 0.5f;
        cs[g] = __cosf(th);
        ss[g] = __sinf(th);
    }
    // load the 4 mo rows for this block
    const int a = blockIdx.x * 4 + wv;
    rows[wv][lane] = mo[(size_t)a * 128 + lane * 2];
    __syncthreads();

    // chunk polynomials: wave wv does gates [wv*144, wv*144+144)
    {
        float p = (lane == 0) ? 1.f : 0.f;
        const int g0 = wv * CHUNK;
        for (int g = 0; g < CHUNK; ++g) {
            float prev = __shfl(p, (lane + 63) & 63);
            p = fmaf(cs[g0 + g], p, ss[g0 + g] * prev);
        }
        pA[wv][lane] = p;
    }
    __syncthreads();
    if (wv < 2) {
        float r = 0.f;
        for (int i = 0; i < 64; ++i)
            r += pA[2 * wv][i] * pA[2 * wv + 1][(lane - i) & 63];
        pB[wv][lane] = r;
    }
    __syncthreads();
    if (wv == 0) {
        float r = 0.f;
        for (int i = 0; i < 64; ++i)
            r += pB[0][i] * pB[1][(lane - i) & 63];
        f[lane] = r;
    }
    __syncthreads();

    // M2 row conv: lane j of wave wv
    float r = 0.f;
    for (int i = 0; i < 64; ++i)
        r = fmaf(f[i], rows[wv][(lane + i) & 63], r);
    M2[(size_t)a * 64 + lane] = r;
}

// k_W1M2: W1M2[j][q] = sum_a w1[j][a] * M2[a][q]   (one j per block)
__global__ void k_W1M2(const float* __restrict__ w1, const float* __restrict__ M2,
                       float* __restrict__ W1M2) {
    __shared__ float red[4][64];
    const int j    = blockIdx.x;           // 64
    const int t    = threadIdx.x;          // 256
    const int lane = t & 63;
    const int wv   = t >> 6;
    float acc = 0.f;
    const float* w1r = w1 + (size_t)j * A_DIM + wv * 256;
    const float* m2p = M2 + (size_t)wv * 256 * 64 + lane;
    for (int a = 0; a < 256; ++a)
        acc = fmaf(w1r[a], m2p[(size_t)a * 64], acc);
    red[wv][lane] = acc;
    __syncthreads();
    if (t < 64)
        W1M2[(size_t)j * 64 + t] = red[0][t] + red[1][t] + red[2][t] + red[3][t];
}

// K1: partial[ks][m][n] — r3-verified GEMM, verbatim
__global__ __launch_bounds__(256, 4) void k_gemm(
        const float* __restrict__ state, const uint4* __restrict__ bpack,
        float* __restrict__ partial) {
    __shared__ __align__(16) uint32 As[2][MT][36];
    const int t  = threadIdx.x;
    const int w  = t >> 6;
    const int l  = t & 63;
    const int m0 = blockIdx.x * MT;
    const int ks = blockIdx.y;
    const int k0 = ks * KC;

    const int ar = t >> 2;
    const int ac = (t & 3) * 16;
    const float* pa = state + (size_t)(m0 + ar) * S_DIM + k0 + ac;
    const uint4* pb = bpack + (size_t)(k0 >> 5) * 4 * 64 + l;

    const int frow = w * 16 + (l & 15);
    const int fc   = (l >> 4) * 4;

    f32x4 acc[4] = {};
    float4 ra0, ra1, ra2, ra3;
#define LOADA(off) do { \
        const float* p_ = pa + (off); \
        ra0 = *(const float4*)(p_);      ra1 = *(const float4*)(p_ + 4); \
        ra2 = *(const float4*)(p_ + 8);  ra3 = *(const float4*)(p_ + 12); } while (0)

#define CVTWRITE(buf) do { \
        uint4 w0, w1; \
        w0.x = pk_f16(ra0.x, ra0.y); w0.y = pk_f16(ra0.z, ra0.w); \
        w0.z = pk_f16(ra1.x, ra1.y); w0.w = pk_f16(ra1.z, ra1.w); \
        w1.x = pk_f16(ra2.x, ra2.y); w1.y = pk_f16(ra2.z, ra2.w); \
        w1.z = pk_f16(ra3.x, ra3.y); w1.w = pk_f16(ra3.z, ra3.w); \
        *(uint4*)&As[buf][ar][ac >> 1]       = w0; \
        *(uint4*)&As[buf][ar][(ac >> 1) + 4] = w1; } while (0)

    LOADA(0);
    CVTWRITE(0);

    for (int s = 0; s < NSTEP; ++s) {
        const int cur = s & 1;
        if (s + 1 < NSTEP) LOADA((s + 1) * BK);
        uint4 bf0[4], bf1[4];
#pragma unroll
        for (int nt = 0; nt < 4; ++nt) {
            bf0[nt] = pb[(size_t)((s * 2 + 0) * 4 + nt) * 64];
            bf1[nt] = pb[(size_t)((s * 2 + 1) * 4 + nt) * 64];
        }
        __syncthreads();
        uint4 af0 = *(const uint4*)&As[cur][frow][fc];
        uint4 af1 = *(const uint4*)&As[cur][frow][fc + 16];
#pragma unroll
        for (int nt = 0; nt < 4; ++nt) {
            acc[nt] = mfma16(af0, bf0[nt], acc[nt]);
            acc[nt] = mfma16(af1, bf1[nt], acc[nt]);
        }
        __syncthreads();
        if (s + 1 < NSTEP) CVTWRITE(cur ^ 1);
    }

    float* pc = partial + (size_t)ks * (B_DIM * Q_DIM);
    const int mr = m0 + w * 16 + (l >> 4) * 4;
    const int nc = l & 15;
#pragma unroll
    for (int nt = 0; nt < 4; ++nt)
#pragma unroll
        for (int r = 0; r < 4; ++r)
            pc[(size_t)(mr + r) * Q_DIM + nt * 16 + nc] = acc[nt][r];
#undef LOADA
#undef CVTWRITE
}

// K2: sum partials + bias; softmax over q; per-block column sums
__global__ void k_softmax(const float* __restrict__ partial,
                          const float* __restrict__ encb,
                          float* __restrict__ colsum_parts) {
    __shared__ float red[4][64];
    const int lane = threadIdx.x & 63;
    const int wv   = threadIdx.x >> 6;
    const float eb = encb[lane];
    float accq = 0.f;
    for (int i = 0; i < 8; ++i) {
        const int r = blockIdx.x * 32 + i * 4 + wv;
        float x = eb;
#pragma unroll
        for (int ks = 0; ks < KSPLIT; ++ks)
            x += partial[(size_t)ks * (B_DIM * Q_DIM) + (size_t)r * Q_DIM + lane];
        float m = x;
        for (int o = 32; o > 0; o >>= 1) m = fmaxf(m, __shfl_xor(m, o));
        float e = __expf(x - m);
        float s = e;
        for (int o = 32; o > 0; o >>= 1) s += __shfl_xor(s, o);
        accq += e / s;
    }
    red[wv][lane] = accq;
    __syncthreads();
    if (threadIdx.x < 64) {
        colsum_parts[blockIdx.x * 64 + lane] =
            red[0][lane] + red[1][lane] + red[2][lane] + red[3][lane];
    }
}

// k_final: 256 blocks; each redundantly reduces colsum -> t0, h = relu(W1M2@t0+b1),
// then computes its own 4 output rows (w2 read in parallel across blocks).
__global__ void k_final(const float* __restrict__ colsum_parts,
                        const float* __restrict__ W1M2,
                        const float* __restrict__ b1,
                        const float* __restrict__ w2, const float* __restrict__ b2,
                        float* __restrict__ out) {
    __shared__ float red[4][64];
    __shared__ float t0[64];
    __shared__ float hl[64];
    const int t    = threadIdx.x;          // 256
    const int lane = t & 63;
    const int wv   = t >> 6;

    float c = 0.f;
#pragma unroll
    for (int i = 0; i < 64; ++i)
        c += colsum_parts[(size_t)(wv * 64 + i) * 64 + lane];
    red[wv][lane] = c;
    __syncthreads();
    if (t < 64)
        t0[t] = red[0][t] + red[1][t] + red[2][t] + red[3][t];
    __syncthreads();
    if (t < 64) {
        float v = 0.f;
        const float* wr = W1M2 + (size_t)t * 64;
#pragma unroll
        for (int q = 0; q < 64; ++q)
            v = fmaf(wr[q], t0[q], v);
        hl[t] = fmaxf(v + b1[t], 0.f);
    }
    __syncthreads();
    const int a = blockIdx.x * 4 + wv;
    float v = w2[(size_t)a * H_DIM + lane] * hl[lane];
    for (int o = 32; o > 0; o >>= 1) v += __shfl_xor(v, o);
    if (lane == 0) out[a] = v + b2[a];
}

extern "C" void kernel_launch(void* const* d_in, const int* in_sizes, int n_in,
                              void* d_out, int out_size, void* d_ws, size_t ws_size,
                              hipStream_t stream) {
    const float* state = (const float*)d_in[0];
    const float* encw  = (const float*)d_in[1];
    const float* encb  = (const float*)d_in[2];
    const float* qp    = (const float*)d_in[3];
    const float* mo    = (const float*)d_in[4];
    const float* w1    = (const float*)d_in[5];
    const float* b1    = (const float*)d_in[6];
    const float* w2    = (const float*)d_in[7];
    const float* b2    = (const float*)d_in[8];
    float* out = (float*)d_out;

    float* ws           = (float*)d_ws;
    float* colsum_parts = ws;                              // 16384
    float* partial      = ws + 16384;                      // 8*524288 (16 MB)
    float* M2           = partial + (size_t)KSPLIT * B_DIM * Q_DIM;  // 65536
    float* W1M2         = M2 + (size_t)A_DIM * 64;         // 4096
    uint4* bpack        = (uint4*)(W1M2 + 4096);           // 65536 uint4 (1 MB)

    // input-only precomputation (off the gemm->out critical path)
    k_packB<<<dim3(256), dim3(256), 0, stream>>>(encw, bpack);
    k_M2<<<dim3(256), dim3(256), 0, stream>>>(qp, mo, M2);
    k_W1M2<<<dim3(64), dim3(256), 0, stream>>>(w1, M2, W1M2);
    // main pipeline
    k_gemm<<<dim3(B_DIM / MT, KSPLIT), dim3(256), 0, stream>>>(state, bpack, partial);
    k_softmax<<<dim3(256), dim3(256), 0, stream>>>(partial, encb, colsum_parts);
    k_final<<<dim3(256), dim3(256), 0, stream>>>(colsum_parts, W1M2, b1, w2, b2, out);
}

// Round 10
// 95.867 us; speedup vs baseline: 1.8482x; 1.0652x over previous
//
#include <hip/hip_runtime.h>
#include <hip/hip_fp16.h>

typedef __fp16 h2_t __attribute__((ext_vector_type(2)));
typedef _Float16 f16x8 __attribute__((ext_vector_type(8)));
typedef float f32x4 __attribute__((ext_vector_type(4)));
typedef unsigned int uint32;

#define S_DIM 8192
#define B_DIM 8192
#define Q_DIM 64
#define A_DIM 1024
#define H_DIM 64
#define N_GATES 576

#define MT 64                  // rows per block
#define KSPLIT 8
#define KC (S_DIM / KSPLIT)    // 1024 k per block
#define BK 64                  // k per staged step
#define NSTEP (KC / BK)        // 16
#define NCHUNK 4
#define CHUNK (N_GATES / NCHUNK)   // 144

__device__ __forceinline__ uint32 pk_f16(float x, float y) {
    h2_t h = __builtin_amdgcn_cvt_pkrtz(x, y);
    return __builtin_bit_cast(uint32, h);
}

__device__ __forceinline__ f32x4 mfma16(uint4 a, uint4 b, f32x4 c) {
    return __builtin_amdgcn_mfma_f32_16x16x32_f16(
        __builtin_bit_cast(f16x8, a), __builtin_bit_cast(f16x8, b), c, 0, 0, 0);
}

// k_pre: one launch for all input-only prep.
//  blocks [0,256):  pack enc_w -> MFMA B-fragment order f16 (r3-verified)
//  blocks [256,320): WM[j][i] = sum_a w1[j][a] * mo[a][2i]  (f-independent fold)
__global__ void k_pre(const float* __restrict__ encw, uint4* __restrict__ bpack,
                      const float* __restrict__ w1, const float* __restrict__ mo,
                      float* __restrict__ WM) {
    const int bid = blockIdx.x;
    const int t   = threadIdx.x;
    if (bid < 256) {
        const int gid  = bid * 256 + t;                 // 65536 total
        const int lane = gid & 63;
        const int nt   = (gid >> 6) & 3;
        const int kt   = gid >> 8;                      // 0..255
        const int n = nt * 16 + (lane & 15);
        const int k = kt * 32 + (lane >> 4) * 8;
        const float* p = encw + (size_t)n * S_DIM + k;
        float4 x0 = *(const float4*)p;
        float4 x1 = *(const float4*)(p + 4);
        uint4 r;
        r.x = pk_f16(x0.x, x0.y);
        r.y = pk_f16(x0.z, x0.w);
        r.z = pk_f16(x1.x, x1.y);
        r.w = pk_f16(x1.z, x1.w);
        bpack[gid] = r;
    } else {
        __shared__ float red[4][64];
        const int j    = bid - 256;                     // 0..63
        const int lane = t & 63;
        const int wv   = t >> 6;                        // 0..3
        const float* w1r = w1 + (size_t)j * A_DIM + wv * 256;
        const float* mop = mo + (size_t)wv * 256 * 128 + lane * 2;
        float acc = 0.f;
        for (int a = 0; a < 256; ++a)
            acc = fmaf(w1r[a], mop[(size_t)a * 128], acc);
        red[wv][lane] = acc;
        __syncthreads();
        if (t < 64)
            WM[(size_t)j * 64 + t] = red[0][t] + red[1][t] + red[2][t] + red[3][t];
    }
}

// K1: partial[ks][m][n] — r3-verified GEMM, verbatim
__global__ __launch_bounds__(256, 4) void k_gemm(
        const float* __restrict__ state, const uint4* __restrict__ bpack,
        float* __restrict__ partial) {
    __shared__ __align__(16) uint32 As[2][MT][36];
    const int t  = threadIdx.x;
    const int w  = t >> 6;
    const int l  = t & 63;
    const int m0 = blockIdx.x * MT;
    const int ks = blockIdx.y;
    const int k0 = ks * KC;

    const int ar = t >> 2;
    const int ac = (t & 3) * 16;
    const float* pa = state + (size_t)(m0 + ar) * S_DIM + k0 + ac;
    const uint4* pb = bpack + (size_t)(k0 >> 5) * 4 * 64 + l;

    const int frow = w * 16 + (l & 15);
    const int fc   = (l >> 4) * 4;

    f32x4 acc[4] = {};
    float4 ra0, ra1, ra2, ra3;
#define LOADA(off) do { \
        const float* p_ = pa + (off); \
        ra0 = *(const float4*)(p_);      ra1 = *(const float4*)(p_ + 4); \
        ra2 = *(const float4*)(p_ + 8);  ra3 = *(const float4*)(p_ + 12); } while (0)

#define CVTWRITE(buf) do { \
        uint4 w0, w1; \
        w0.x = pk_f16(ra0.x, ra0.y); w0.y = pk_f16(ra0.z, ra0.w); \
        w0.z = pk_f16(ra1.x, ra1.y); w0.w = pk_f16(ra1.z, ra1.w); \
        w1.x = pk_f16(ra2.x, ra2.y); w1.y = pk_f16(ra2.z, ra2.w); \
        w1.z = pk_f16(ra3.x, ra3.y); w1.w = pk_f16(ra3.z, ra3.w); \
        *(uint4*)&As[buf][ar][ac >> 1]       = w0; \
        *(uint4*)&As[buf][ar][(ac >> 1) + 4] = w1; } while (0)

    LOADA(0);
    CVTWRITE(0);

    for (int s = 0; s < NSTEP; ++s) {
        const int cur = s & 1;
        if (s + 1 < NSTEP) LOADA((s + 1) * BK);
        uint4 bf0[4], bf1[4];
#pragma unroll
        for (int nt = 0; nt < 4; ++nt) {
            bf0[nt] = pb[(size_t)((s * 2 + 0) * 4 + nt) * 64];
            bf1[nt] = pb[(size_t)((s * 2 + 1) * 4 + nt) * 64];
        }
        __syncthreads();
        uint4 af0 = *(const uint4*)&As[cur][frow][fc];
        uint4 af1 = *(const uint4*)&As[cur][frow][fc + 16];
#pragma unroll
        for (int nt = 0; nt < 4; ++nt) {
            acc[nt] = mfma16(af0, bf0[nt], acc[nt]);
            acc[nt] = mfma16(af1, bf1[nt], acc[nt]);
        }
        __syncthreads();
        if (s + 1 < NSTEP) CVTWRITE(cur ^ 1);
    }

    float* pc = partial + (size_t)ks * (B_DIM * Q_DIM);
    const int mr = m0 + w * 16 + (l >> 4) * 4;
    const int nc = l & 15;
#pragma unroll
    for (int nt = 0; nt < 4; ++nt)
#pragma unroll
        for (int r = 0; r < 4; ++r)
            pc[(size_t)(mr + r) * Q_DIM + nt * 16 + nc] = acc[nt][r];
#undef LOADA
#undef CVTWRITE
}

// K2: sum partials + bias; softmax over q; per-block column sums
__global__ void k_softmax(const float* __restrict__ partial,
                          const float* __restrict__ encb,
                          float* __restrict__ colsum_parts) {
    __shared__ float red[4][64];
    const int lane = threadIdx.x & 63;
    const int wv   = threadIdx.x >> 6;
    const float eb = encb[lane];
    float accq = 0.f;
    for (int i = 0; i < 8; ++i) {
        const int r = blockIdx.x * 32 + i * 4 + wv;
        float x = eb;
#pragma unroll
        for (int ks = 0; ks < KSPLIT; ++ks)
            x += partial[(size_t)ks * (B_DIM * Q_DIM) + (size_t)r * Q_DIM + lane];
        float m = x;
        for (int o = 32; o > 0; o >>= 1) m = fmaxf(m, __shfl_xor(m, o));
        float e = __expf(x - m);
        float s = e;
        for (int o = 32; o > 0; o >>= 1) s += __shfl_xor(s, o);
        accq += e / s;
    }
    red[wv][lane] = accq;
    __syncthreads();
    if (threadIdx.x < 64) {
        colsum_parts[blockIdx.x * 64 + lane] =
            red[0][lane] + red[1][lane] + red[2][lane] + red[3][lane];
    }
}

// k_final: 256 blocks; each block redundantly: reduce t0, gate filter f (chunked
// polys + conv tree), g = conv(f,t0), h = relu(WM@g+b1), then its 4 out rows.
__global__ void k_final(const float* __restrict__ colsum_parts,
                        const float* __restrict__ qp,
                        const float* __restrict__ WM,
                        const float* __restrict__ b1,
                        const float* __restrict__ w2, const float* __restrict__ b2,
                        float* __restrict__ out) {
    __shared__ float red[4][64];
    __shared__ float t0[64];
    __shared__ float cs[N_GATES], ss[N_GATES];
    __shared__ float pA[NCHUNK][64];
    __shared__ float pB[2][64];
    __shared__ float fv[64];
    __shared__ float gv[64];
    __shared__ float hl[64];
    const int t    = threadIdx.x;          // 256
    const int lane = t & 63;
    const int wv   = t >> 6;               // 0..3

    for (int g = t; g < N_GATES; g += 256) {
        float th = qp[g] * 0.5f;
        cs[g] = __cosf(th);
        ss[g] = __sinf(th);
    }
    {
        float c = 0.f;
#pragma unroll
        for (int i = 0; i < 64; ++i)
            c += colsum_parts[(size_t)(wv * 64 + i) * 64 + lane];
        red[wv][lane] = c;
    }
    __syncthreads();
    if (t < 64)
        t0[t] = red[0][t] + red[1][t] + red[2][t] + red[3][t];
    // chunk polynomials (cs/ss ready after the sync above)
    {
        float p = (lane == 0) ? 1.f : 0.f;
        const int g0 = wv * CHUNK;
        for (int g = 0; g < CHUNK; ++g) {
            float prev = __shfl(p, (lane + 63) & 63);
            p = fmaf(cs[g0 + g], p, ss[g0 + g] * prev);
        }
        pA[wv][lane] = p;
    }
    __syncthreads();
    if (wv < 2) {
        float r = 0.f;
        for (int i = 0; i < 64; ++i)
            r += pA[2 * wv][i] * pA[2 * wv + 1][(lane - i) & 63];
        pB[wv][lane] = r;
    }
    __syncthreads();
    if (wv == 0) {
        float r = 0.f;
        for (int i = 0; i < 64; ++i)
            r += pB[0][i] * pB[1][(lane - i) & 63];
        fv[lane] = r;
    }
    __syncthreads();
    if (wv == 0) {
        float r = 0.f;
        for (int i = 0; i < 64; ++i)
            r += fv[i] * t0[(lane - i) & 63];
        gv[lane] = r;
    }
    __syncthreads();
    if (t < 64) {
        float v = 0.f;
        const float* wr = WM + (size_t)t * 64;
#pragma unroll
        for (int q = 0; q < 64; ++q)
            v = fmaf(wr[q], gv[q], v);
        hl[t] = fmaxf(v + b1[t], 0.f);
    }
    __syncthreads();
    const int a = blockIdx.x * 4 + wv;
    float v = w2[(size_t)a * H_DIM + lane] * hl[lane];
    for (int o = 32; o > 0; o >>= 1) v += __shfl_xor(v, o);
    if (lane == 0) out[a] = v + b2[a];
}

extern "C" void kernel_launch(void* const* d_in, const int* in_sizes, int n_in,
                              void* d_out, int out_size, void* d_ws, size_t ws_size,
                              hipStream_t stream) {
    const float* state = (const float*)d_in[0];
    const float* encw  = (const float*)d_in[1];
    const float* encb  = (const float*)d_in[2];
    const float* qp    = (const float*)d_in[3];
    const float* mo    = (const float*)d_in[4];
    const float* w1    = (const float*)d_in[5];
    const float* b1    = (const float*)d_in[6];
    const float* w2    = (const float*)d_in[7];
    const float* b2    = (const float*)d_in[8];
    float* out = (float*)d_out;

    float* ws           = (float*)d_ws;
    float* colsum_parts = ws;                              // 16384 floats
    float* partial      = ws + 16384;                      // 8*524288 (16 MB)
    float* WM           = partial + (size_t)KSPLIT * B_DIM * Q_DIM;  // 4096
    uint4* bpack        = (uint4*)(WM + 4096);             // 65536 uint4 (1 MB)

    k_pre<<<dim3(320), dim3(256), 0, stream>>>(encw, bpack, w1, mo, WM);
    k_gemm<<<dim3(B_DIM / MT, KSPLIT), dim3(256), 0, stream>>>(state, bpack, partial);
    k_softmax<<<dim3(256), dim3(256), 0, stream>>>(partial, encb, colsum_parts);
    k_final<<<dim3(256), dim3(256), 0, stream>>>(colsum_parts, qp, WM, b1, w2, b2, out);
}

// Round 11
// 95.142 us; speedup vs baseline: 1.8623x; 1.0076x over previous
//
#include <hip/hip_runtime.h>
#include <hip/hip_fp16.h>

typedef __fp16 h2_t __attribute__((ext_vector_type(2)));
typedef _Float16 f16x8 __attribute__((ext_vector_type(8)));
typedef float f32x4 __attribute__((ext_vector_type(4)));
typedef unsigned int uint32;

#define S_DIM 8192
#define B_DIM 8192
#define Q_DIM 64
#define A_DIM 1024
#define H_DIM 64
#define N_GATES 576

#define MT 64                  // rows per block
#define KSPLIT 8
#define KC (S_DIM / KSPLIT)    // 1024 k per block
#define BK 64                  // k per staged step
#define NSTEP (KC / BK)        // 16
#define NCHUNK 4
#define CHUNK (N_GATES / NCHUNK)   // 144

__device__ __forceinline__ uint32 pk_f16(float x, float y) {
    h2_t h = __builtin_amdgcn_cvt_pkrtz(x, y);
    return __builtin_bit_cast(uint32, h);
}

__device__ __forceinline__ f32x4 mfma16(uint4 a, uint4 b, f32x4 c) {
    return __builtin_amdgcn_mfma_f32_16x16x32_f16(
        __builtin_bit_cast(f16x8, a), __builtin_bit_cast(f16x8, b), c, 0, 0, 0);
}

// k_pre: one launch for all input-only prep.
//  blocks [0,256):  pack enc_w -> MFMA B-fragment order f16 (r3-verified)
//  blocks [256,320): WM[j][i] = sum_a w1[j][a] * mo[a][2i]  (f-independent fold)
__global__ void k_pre(const float* __restrict__ encw, uint4* __restrict__ bpack,
                      const float* __restrict__ w1, const float* __restrict__ mo,
                      float* __restrict__ WM) {
    const int bid = blockIdx.x;
    const int t   = threadIdx.x;
    if (bid < 256) {
        const int gid  = bid * 256 + t;                 // 65536 total
        const int lane = gid & 63;
        const int nt   = (gid >> 6) & 3;
        const int kt   = gid >> 8;                      // 0..255
        const int n = nt * 16 + (lane & 15);
        const int k = kt * 32 + (lane >> 4) * 8;
        const float* p = encw + (size_t)n * S_DIM + k;
        float4 x0 = *(const float4*)p;
        float4 x1 = *(const float4*)(p + 4);
        uint4 r;
        r.x = pk_f16(x0.x, x0.y);
        r.y = pk_f16(x0.z, x0.w);
        r.z = pk_f16(x1.x, x1.y);
        r.w = pk_f16(x1.z, x1.w);
        bpack[gid] = r;
    } else {
        __shared__ float red[4][64];
        const int j    = bid - 256;                     // 0..63
        const int lane = t & 63;
        const int wv   = t >> 6;                        // 0..3
        const float* w1r = w1 + (size_t)j * A_DIM + wv * 256;
        const float* mop = mo + (size_t)wv * 256 * 128 + lane * 2;
        float acc = 0.f;
        for (int a = 0; a < 256; ++a)
            acc = fmaf(w1r[a], mop[(size_t)a * 128], acc);
        red[wv][lane] = acc;
        __syncthreads();
        if (t < 64)
            WM[(size_t)j * 64 + t] = red[0][t] + red[1][t] + red[2][t] + red[3][t];
    }
}

// K1: partial[ks][m][n] — r3-verified GEMM; ONLY change vs r9: the two
// per-step barriers are raw s_barrier + lgkmcnt(0) (no vmcnt drain), so the
// A prefetch issued each step stays in flight across the barrier.
__global__ __launch_bounds__(256, 4) void k_gemm(
        const float* __restrict__ state, const uint4* __restrict__ bpack,
        float* __restrict__ partial) {
    __shared__ __align__(16) uint32 As[2][MT][36];
    const int t  = threadIdx.x;
    const int w  = t >> 6;
    const int l  = t & 63;
    const int m0 = blockIdx.x * MT;
    const int ks = blockIdx.y;
    const int k0 = ks * KC;

    const int ar = t >> 2;
    const int ac = (t & 3) * 16;
    const float* pa = state + (size_t)(m0 + ar) * S_DIM + k0 + ac;
    const uint4* pb = bpack + (size_t)(k0 >> 5) * 4 * 64 + l;

    const int frow = w * 16 + (l & 15);
    const int fc   = (l >> 4) * 4;

    f32x4 acc[4] = {};
    float4 ra0, ra1, ra2, ra3;
#define LOADA(off) do { \
        const float* p_ = pa + (off); \
        ra0 = *(const float4*)(p_);      ra1 = *(const float4*)(p_ + 4); \
        ra2 = *(const float4*)(p_ + 8);  ra3 = *(const float4*)(p_ + 12); } while (0)

#define CVTWRITE(buf) do { \
        uint4 w0, w1; \
        w0.x = pk_f16(ra0.x, ra0.y); w0.y = pk_f16(ra0.z, ra0.w); \
        w0.z = pk_f16(ra1.x, ra1.y); w0.w = pk_f16(ra1.z, ra1.w); \
        w1.x = pk_f16(ra2.x, ra2.y); w1.y = pk_f16(ra2.z, ra2.w); \
        w1.z = pk_f16(ra3.x, ra3.y); w1.w = pk_f16(ra3.z, ra3.w); \
        *(uint4*)&As[buf][ar][ac >> 1]       = w0; \
        *(uint4*)&As[buf][ar][(ac >> 1) + 4] = w1; } while (0)

// LDS-visibility barrier that does NOT drain outstanding global loads
#define LBAR() do { \
        asm volatile("s_waitcnt lgkmcnt(0)" ::: "memory"); \
        __builtin_amdgcn_s_barrier(); \
        __builtin_amdgcn_sched_barrier(0); } while (0)

    LOADA(0);
    CVTWRITE(0);

    for (int s = 0; s < NSTEP; ++s) {
        const int cur = s & 1;
        if (s + 1 < NSTEP) LOADA((s + 1) * BK);
        uint4 bf0[4], bf1[4];
#pragma unroll
        for (int nt = 0; nt < 4; ++nt) {
            bf0[nt] = pb[(size_t)((s * 2 + 0) * 4 + nt) * 64];
            bf1[nt] = pb[(size_t)((s * 2 + 1) * 4 + nt) * 64];
        }
        LBAR();                                   // As[cur] writes visible
        uint4 af0 = *(const uint4*)&As[cur][frow][fc];
        uint4 af1 = *(const uint4*)&As[cur][frow][fc + 16];
#pragma unroll
        for (int nt = 0; nt < 4; ++nt) {
            acc[nt] = mfma16(af0, bf0[nt], acc[nt]);
            acc[nt] = mfma16(af1, bf1[nt], acc[nt]);
        }
        LBAR();                                   // reads done before overwrite
        if (s + 1 < NSTEP) CVTWRITE(cur ^ 1);
    }

    float* pc = partial + (size_t)ks * (B_DIM * Q_DIM);
    const int mr = m0 + w * 16 + (l >> 4) * 4;
    const int nc = l & 15;
#pragma unroll
    for (int nt = 0; nt < 4; ++nt)
#pragma unroll
        for (int r = 0; r < 4; ++r)
            pc[(size_t)(mr + r) * Q_DIM + nt * 16 + nc] = acc[nt][r];
#undef LOADA
#undef CVTWRITE
#undef LBAR
}

// K2: sum partials + bias; softmax over q; per-block column sums
__global__ void k_softmax(const float* __restrict__ partial,
                          const float* __restrict__ encb,
                          float* __restrict__ colsum_parts) {
    __shared__ float red[4][64];
    const int lane = threadIdx.x & 63;
    const int wv   = threadIdx.x >> 6;
    const float eb = encb[lane];
    float accq = 0.f;
    for (int i = 0; i < 8; ++i) {
        const int r = blockIdx.x * 32 + i * 4 + wv;
        float x = eb;
#pragma unroll
        for (int ks = 0; ks < KSPLIT; ++ks)
            x += partial[(size_t)ks * (B_DIM * Q_DIM) + (size_t)r * Q_DIM + lane];
        float m = x;
        for (int o = 32; o > 0; o >>= 1) m = fmaxf(m, __shfl_xor(m, o));
        float e = __expf(x - m);
        float s = e;
        for (int o = 32; o > 0; o >>= 1) s += __shfl_xor(s, o);
        accq += e / s;
    }
    red[wv][lane] = accq;
    __syncthreads();
    if (threadIdx.x < 64) {
        colsum_parts[blockIdx.x * 64 + lane] =
            red[0][lane] + red[1][lane] + red[2][lane] + red[3][lane];
    }
}

// k_final: 256 blocks; each block redundantly: reduce t0, gate filter f (chunked
// polys + conv tree), g = conv(f,t0), h = relu(WM@g+b1), then its 4 out rows.
__global__ void k_final(const float* __restrict__ colsum_parts,
                        const float* __restrict__ qp,
                        const float* __restrict__ WM,
                        const float* __restrict__ b1,
                        const float* __restrict__ w2, const float* __restrict__ b2,
                        float* __restrict__ out) {
    __shared__ float red[4][64];
    __shared__ float t0[64];
    __shared__ float cs[N_GATES], ss[N_GATES];
    __shared__ float pA[NCHUNK][64];
    __shared__ float pB[2][64];
    __shared__ float fv[64];
    __shared__ float gv[64];
    __shared__ float hl[64];
    const int t    = threadIdx.x;          // 256
    const int lane = t & 63;
    const int wv   = t >> 6;               // 0..3

    for (int g = t; g < N_GATES; g += 256) {
        float th = qp[g] * 0.5f;
        cs[g] = __cosf(th);
        ss[g] = __sinf(th);
    }
    {
        float c = 0.f;
#pragma unroll
        for (int i = 0; i < 64; ++i)
            c += colsum_parts[(size_t)(wv * 64 + i) * 64 + lane];
        red[wv][lane] = c;
    }
    __syncthreads();
    if (t < 64)
        t0[t] = red[0][t] + red[1][t] + red[2][t] + red[3][t];
    // chunk polynomials (cs/ss ready after the sync above)
    {
        float p = (lane == 0) ? 1.f : 0.f;
        const int g0 = wv * CHUNK;
        for (int g = 0; g < CHUNK; ++g) {
            float prev = __shfl(p, (lane + 63) & 63);
            p = fmaf(cs[g0 + g], p, ss[g0 + g] * prev);
        }
        pA[wv][lane] = p;
    }
    __syncthreads();
    if (wv < 2) {
        float r = 0.f;
        for (int i = 0; i < 64; ++i)
            r += pA[2 * wv][i] * pA[2 * wv + 1][(lane - i) & 63];
        pB[wv][lane] = r;
    }
    __syncthreads();
    if (wv == 0) {
        float r = 0.f;
        for (int i = 0; i < 64; ++i)
            r += pB[0][i] * pB[1][(lane - i) & 63];
        fv[lane] = r;
    }
    __syncthreads();
    if (wv == 0) {
        float r = 0.f;
        for (int i = 0; i < 64; ++i)
            r += fv[i] * t0[(lane - i) & 63];
        gv[lane] = r;
    }
    __syncthreads();
    if (t < 64) {
        float v = 0.f;
        const float* wr = WM + (size_t)t * 64;
#pragma unroll
        for (int q = 0; q < 64; ++q)
            v = fmaf(wr[q], gv[q], v);
        hl[t] = fmaxf(v + b1[t], 0.f);
    }
    __syncthreads();
    const int a = blockIdx.x * 4 + wv;
    float v = w2[(size_t)a * H_DIM + lane] * hl[lane];
    for (int o = 32; o > 0; o >>= 1) v += __shfl_xor(v, o);
    if (lane == 0) out[a] = v + b2[a];
}

extern "C" void kernel_launch(void* const* d_in, const int* in_sizes, int n_in,
                              void* d_out, int out_size, void* d_ws, size_t ws_size,
                              hipStream_t stream) {
    const float* state = (const float*)d_in[0];
    const float* encw  = (const float*)d_in[1];
    const float* encb  = (const float*)d_in[2];
    const float* qp    = (const float*)d_in[3];
    const float* mo    = (const float*)d_in[4];
    const float* w1    = (const float*)d_in[5];
    const float* b1    = (const float*)d_in[6];
    const float* w2    = (const float*)d_in[7];
    const float* b2    = (const float*)d_in[8];
    float* out = (float*)d_out;

    float* ws           = (float*)d_ws;
    float* colsum_parts = ws;                              // 16384 floats
    float* partial      = ws + 16384;                      // 8*524288 (16 MB)
    float* WM           = partial + (size_t)KSPLIT * B_DIM * Q_DIM;  // 4096
    uint4* bpack        = (uint4*)(WM + 4096);             // 65536 uint4 (1 MB)

    k_pre<<<dim3(320), dim3(256), 0, stream>>>(encw, bpack, w1, mo, WM);
    k_gemm<<<dim3(B_DIM / MT, KSPLIT), dim3(256), 0, stream>>>(state, bpack, partial);
    k_softmax<<<dim3(256), dim3(256), 0, stream>>>(partial, encb, colsum_parts);
    k_final<<<dim3(256), dim3(256), 0, stream>>>(colsum_parts, qp, WM, b1, w2, b2, out);
}